// Round 3
// baseline (888.815 us; speedup 1.0000x reference)
//
#include <hip/hip_runtime.h>
#include <hip/hip_bf16.h>

#define N_GRAPHS 4096
#define N_ELE 16384
#define EPS 1e-5f

// ws layout (f32 words)
#define A_TAB_OFF 0               // 4096*64 f32 atomic sums
#define A_CNT_OFF 262144          // 4096
#define E_TAB_OFF 266240          // 16384*64
#define E_CNT_OFF 1314816         // 16384
#define STAT_OFF  1331200         // 32 copies * (256 sums + 256 sqs)
#define ZERO_WORDS 1347584        // memset range: everything above
#define A_TABH_OFF 1347584        // 4096*64 bf16 = 131072 words
#define E_TABH_OFF 1478656        // 16384*64 bf16 = 524288 words
#define W1PK_OFF  2002944         // 128*192 bf16 = 12288 words (W2 right after)
#define FCPK_OFF  2027520         // 128*256 bf16 = 16384 words
#define SCALE_OFF 2043904         // 256
#define SHIFT_OFF 2044160         // 256
#define WS_WORDS  2044416         // ~8.2 MB

typedef __attribute__((ext_vector_type(8))) short bf16x8;
typedef __attribute__((ext_vector_type(4))) float f32x4;

__device__ __forceinline__ float bf2f(unsigned s) { return __uint_as_float(s << 16); }
__device__ __forceinline__ unsigned f2bf(float f) {
  unsigned u = __float_as_uint(f);
  return (u + 0x7fffu + ((u >> 16) & 1u)) >> 16;  // RNE (host-side packing kernels)
}
__device__ __forceinline__ unsigned pkbf(float a, float b) {
  union { __hip_bfloat16 h; unsigned short u; } ca, cb;
  ca.h = __float2bfloat16(a); cb.h = __float2bfloat16(b);
  return (unsigned)ca.u | ((unsigned)cb.u << 16);
}

// z-staging swizzle: chunk c (16B units, 0..31) of row r -> swizzled chunk
// slot = (c>>2) ^ r ^ (c&3)  (3 bits), upper bits from c&3.
// Epilogue swizzle: slotE = (c ^ r) & 7, upper bits c&24.

// ---------------- K0: pack W1,W2,fcW to bf16 in MFMA B-fragment order ----------------
__global__ void k_prep(const float* __restrict__ W1, const float* __restrict__ W2,
                       const float* __restrict__ fcW, float* __restrict__ ws) {
  int tid = blockIdx.x * 512 + threadIdx.x;
  if (tid < 49152) {
    unsigned short* wpk = (unsigned short*)(ws + W1PK_OFF);
    int L = tid / 24576, rem = tid % 24576;
    int ct = rem / 3072, rem2 = rem % 3072;
    int i = rem2 >> 9, lane = (rem2 >> 3) & 63, j = rem2 & 7;
    int zkb = L ? (i + 2) : (i < 2 ? i : i + 2);
    int zk = zkb * 32 + ((lane >> 4) << 3) + j;
    int kp = L ? (zk - 64) : (zk < 64 ? zk : zk - 64);
    int col = ct * 16 + (lane & 15);
    const float* W = L ? W2 : W1;
    wpk[tid] = (unsigned short)f2bf(W[col * 192 + kp]);
  } else {
    int idx = tid - 49152;
    unsigned short* fpk = (unsigned short*)(ws + FCPK_OFF);
    int ct = idx >> 12, kb = (idx >> 9) & 7, lane = (idx >> 3) & 63, j = idx & 7;
    fpk[idx] = (unsigned short)f2bf(fcW[(ct * 16 + (lane & 15)) * 256 + kb * 32 + ((lane >> 4) << 3) + j]);
  }
}

// ---------------- K1: segment sums ----------------
__global__ void k_seg(const float* __restrict__ x, const int* __restrict__ aidx,
                      const int* __restrict__ eidx, float* __restrict__ ws, int N) {
  float* A_tab = ws + A_TAB_OFF; float* A_cnt = ws + A_CNT_OFF;
  float* E_tab = ws + E_TAB_OFF; float* E_cnt = ws + E_CNT_OFF;
  int t = threadIdx.x;
  int c = t & 63, p = (t >> 6) & 1, s = t >> 7;
  int r0 = blockIdx.x * 256;
  int rend = min(r0 + 256, N);
  if (p == 0) {
    float acc = 0.f, cnt = 0.f; int cur = -1;
    for (int r = r0 + s; r < rend; r += 2) {
      int a = aidx[r];
      float v = x[(size_t)r * 128 + c];
      if (a != cur) {
        if (cur >= 0) { atomicAdd(&A_tab[cur * 64 + c], acc); if (c == 0) atomicAdd(&A_cnt[cur], cnt); }
        cur = a; acc = v; cnt = 1.f;
      } else { acc += v; cnt += 1.f; }
    }
    if (cur >= 0) { atomicAdd(&A_tab[cur * 64 + c], acc); if (c == 0) atomicAdd(&A_cnt[cur], cnt); }
  } else {
    for (int r = r0 + s; r < rend; r += 2) {
      int e = eidx[r];
      float v = x[(size_t)r * 128 + 64 + c];
      atomicAdd(&E_tab[e * 64 + c], v);
      if (c == 0) atomicAdd(&E_cnt[e], 1.f);
    }
  }
}

// ---------------- K2: mean + relu -> bf16 tables ----------------
__global__ void k_fin(float* __restrict__ ws) {
  int i = blockIdx.x * 256 + threadIdx.x;
  unsigned* w32 = (unsigned*)ws;
  if (i < 131072) {
    int e = 2 * i;
    float cnt = fmaxf(ws[A_CNT_OFF + (e >> 6)], 1.f);
    float v0 = fmaxf(ws[A_TAB_OFF + e] / cnt, 0.f);
    float v1 = fmaxf(ws[A_TAB_OFF + e + 1] / cnt, 0.f);
    w32[A_TABH_OFF + i] = f2bf(v0) | (f2bf(v1) << 16);
  }
  if (i < 524288) {
    int e = 2 * i;
    float cnt = fmaxf(ws[E_CNT_OFF + (e >> 6)], 1.f);
    float v0 = fmaxf(ws[E_TAB_OFF + e] / cnt, 0.f);
    float v1 = fmaxf(ws[E_TAB_OFF + e + 1] / cnt, 0.f);
    w32[E_TABH_OFF + i] = f2bf(v0) | (f2bf(v1) << 16);
  }
}

// ---- staging helpers (shared by k_gemm) ----
__device__ __forceinline__ void load_tile(const float* __restrict__ rdf, const float* __restrict__ bdf,
    const unsigned short* __restrict__ Atabh, const unsigned short* __restrict__ Etabh,
    int row, bool ok, int g, int idx, float4* fv) {
  if (g < 4) {
    if (ok) {
      const float4* src = (const float4*)(((g < 2) ? rdf : bdf) + (size_t)row * 64 + (g & 1) * 32);
      #pragma unroll
      for (int i = 0; i < 8; ++i) fv[i] = src[i];
    } else {
      #pragma unroll
      for (int i = 0; i < 8; ++i) fv[i] = (float4){0.f, 0.f, 0.f, 0.f};
    }
  } else {
    if (ok) {
      const float4* src = (const float4*)(((g < 6) ? Atabh : Etabh) + (size_t)idx * 64 + (g & 1) * 32);
      #pragma unroll
      for (int i = 0; i < 4; ++i) fv[i] = src[i];
    } else {
      #pragma unroll
      for (int i = 0; i < 4; ++i) fv[i] = (float4){0.f, 0.f, 0.f, 0.f};
    }
  }
}

__device__ __forceinline__ void cvt_write(char* buf, int r, int g, const float4* fv) {
  unsigned wv[16];
  if (g < 4) {
    #pragma unroll
    for (int i = 0; i < 8; ++i) {
      wv[2 * i]     = pkbf(fv[i].x, fv[i].y);
      wv[2 * i + 1] = pkbf(fv[i].z, fv[i].w);
    }
  } else {
    #pragma unroll
    for (int i = 0; i < 4; ++i) ((float4*)wv)[i] = fv[i];
  }
  #pragma unroll
  for (int i = 0; i < 4; ++i) {
    int slot = ((g ^ r ^ i) & 7) | (i << 3);
    *(uint4*)(buf + r * 512 + slot * 16) = ((uint4*)wv)[i];
  }
}

// ---------------- K3: persistent pipelined MFMA dual GEMM + fused BN stats ----------------
__global__ __launch_bounds__(512, 4) void k_gemm(
    const float* __restrict__ rdf, const float* __restrict__ bdf,
    const int* __restrict__ aidx, const int* __restrict__ eidx,
    float* __restrict__ ws, unsigned* __restrict__ outp, int N, int nT) {
  __shared__ __align__(16) char smem[65536];
  const unsigned short* Atabh = (const unsigned short*)(ws + A_TABH_OFF);
  const unsigned short* Etabh = (const unsigned short*)(ws + E_TABH_OFF);
  int t = threadIdx.x;
  int l = t & 63, w = t >> 6;
  int r = t >> 3, g = t & 7;
  int L = w >> 2, ctp = w & 3;
  const unsigned short* WpkL = (const unsigned short*)(ws + W1PK_OFF) + L * 24576;
  float* stat = ws + STAT_OFF + (blockIdx.x & 31) * 512;
  int step = gridDim.x;
  int tile = blockIdx.x;
  float4 fv[8];
  // prologue: load tile0, prefetch idx(tile+step)
  {
    int row = tile * 64 + r; bool ok = row < N;
    int idx0 = 0;
    if (g >= 4 && ok) idx0 = ((g < 6) ? aidx : eidx)[row];
    load_tile(rdf, bdf, Atabh, Etabh, row, ok, g, idx0, fv);
  }
  int idxN = 0;
  {
    int t2 = tile + step; int row2 = t2 * 64 + r;
    if (g >= 4 && t2 < nT && row2 < N) idxN = ((g < 6) ? aidx : eidx)[row2];
  }
  cvt_write(smem, r, g, fv);
  __syncthreads();
  int cur = 0;
  while (true) {
    int nxt = tile + step;
    bool hasN = nxt < nT;
    int idxN2 = 0;
    if (hasN) {
      int row = nxt * 64 + r; bool ok = row < N;
      load_tile(rdf, bdf, Atabh, Etabh, row, ok, g, idxN, fv);   // issue early; wait deferred
      int t3 = nxt + step; int row3 = t3 * 64 + r;
      if (g >= 4 && t3 < nT && row3 < N) idxN2 = ((g < 6) ? aidx : eidx)[row3];
    }
    // ---- MFMA on buf[cur] ----
    char* buf = smem + cur * 32768;
    f32x4 acc[4][2];
    #pragma unroll
    for (int mt = 0; mt < 4; ++mt)
      #pragma unroll
      for (int cti = 0; cti < 2; ++cti) acc[mt][cti] = (f32x4){0.f, 0.f, 0.f, 0.f};
    #pragma unroll
    for (int i = 0; i < 6; ++i) {
      int zkb = L ? (i + 2) : (i < 2 ? i : i + 2);
      bf16x8 af[4];
      #pragma unroll
      for (int mt = 0; mt < 4; ++mt) {
        int rr = mt * 16 + (l & 15);
        int slot = ((zkb ^ rr ^ (l >> 4)) & 7) | ((l >> 4) << 3);
        af[mt] = *(const bf16x8*)(buf + rr * 512 + slot * 16);
      }
      #pragma unroll
      for (int cti = 0; cti < 2; ++cti) {
        bf16x8 bfr = *(const bf16x8*)(WpkL + (((ctp * 2 + cti) * 6 + i) * 64 + l) * 8);
        #pragma unroll
        for (int mt = 0; mt < 4; ++mt)
          acc[mt][cti] = __builtin_amdgcn_mfma_f32_16x16x32_bf16(af[mt], bfr, acc[mt][cti], 0, 0, 0);
      }
    }
    // ---- fused BN stats ----
    #pragma unroll
    for (int cti = 0; cti < 2; ++cti) {
      float s = 0.f, q = 0.f;
      #pragma unroll
      for (int mt = 0; mt < 4; ++mt)
        #pragma unroll
        for (int rr = 0; rr < 4; ++rr) { float v = acc[mt][cti][rr]; s += v; q += v * v; }
      s += __shfl_xor(s, 16); s += __shfl_xor(s, 32);
      q += __shfl_xor(q, 16); q += __shfl_xor(q, 32);
      if (l < 16) {
        int gc = L * 128 + ctp * 32 + cti * 16 + l;
        atomicAdd(&stat[gc], s);
        atomicAdd(&stat[256 + gc], q);
      }
    }
    __syncthreads();   // all waves done reading buf[cur]
    // ---- epilogue: pack bf16 pairs, swizzled LDS transpose ----
    #pragma unroll
    for (int mt = 0; mt < 4; ++mt)
      #pragma unroll
      for (int cti = 0; cti < 2; ++cti)
        #pragma unroll
        for (int rr = 0; rr < 4; ++rr) {
          unsigned ub = pkbf(acc[mt][cti][rr], 0.f) & 0xffffu;
          unsigned pb = (unsigned)__shfl_xor((int)ub, 1);
          if (!(l & 1)) {
            int orow = mt * 16 + ((l >> 4) << 2) + rr;
            int colp = (L * 128 + ctp * 32 + cti * 16 + (l & 15)) >> 1;
            int c = colp >> 2;
            int ec = ((c ^ orow) & 7) | (c & 24);
            *(unsigned*)(buf + orow * 512 + ec * 16 + (colp & 3) * 4) = ub | (pb << 16);
          }
        }
    __syncthreads();
    // ---- coalesced h store + stage next tile ----
    int row0 = tile * 64;
    #pragma unroll
    for (int p = 0; p < 4; ++p) {
      int e = p * 512 + t; int rr = e >> 5, v4 = e & 31;
      int ec = ((v4 ^ rr) & 7) | (v4 & 24);
      uint4 val = *(const uint4*)(buf + rr * 512 + ec * 16);
      if (row0 + rr < N) ((uint4*)outp)[(size_t)(row0 + rr) * 32 + v4] = val;
    }
    if (!hasN) break;
    cvt_write(smem + (cur ^ 1) * 32768, r, g, fv);   // vmcnt wait lands here
    __syncthreads();
    tile = nxt; cur ^= 1; idxN = idxN2;
  }
}

// ---------------- K4: BN finalize -> scale/shift ----------------
__global__ void k_bnfin(const float* __restrict__ g1, const float* __restrict__ b1,
                        const float* __restrict__ g2, const float* __restrict__ b2,
                        float* __restrict__ ws, int N) {
  int c = threadIdx.x;  // 256
  float s = 0.f, q = 0.f;
  for (int m = 0; m < 32; ++m) { s += ws[STAT_OFF + m * 512 + c]; q += ws[STAT_OFF + m * 512 + 256 + c]; }
  float inv = 1.f / (float)N;
  float mu = s * inv;
  float var = fmaxf(q * inv - mu * mu, 0.f);
  int lyr = c >> 7, cc = c & 127;
  float ga = lyr ? g2[cc] : g1[cc];
  float be = lyr ? b2[cc] : b1[cc];
  float sc = ga * rsqrtf(var + EPS);
  ws[SCALE_OFF + c] = sc;
  ws[SHIFT_OFF + c] = be - mu * sc;
}

// ---- k_fc staging helpers ----
__device__ __forceinline__ void load_fc(const unsigned* __restrict__ hp, const float* __restrict__ x,
    int row, bool ok, int g, uint4* hv, float4* xv) {
  if (ok) {
    const uint4* hs = (const uint4*)(hp + (size_t)row * 128 + g * 16);
    #pragma unroll
    for (int i = 0; i < 4; ++i) hv[i] = hs[i];
    const float4* xs = (const float4*)(x + (size_t)row * 128 + (g & 3) * 32);
    #pragma unroll
    for (int i = 0; i < 8; ++i) xv[i] = xs[i];
  } else {
    #pragma unroll
    for (int i = 0; i < 4; ++i) hv[i] = (uint4){0u, 0u, 0u, 0u};
    #pragma unroll
    for (int i = 0; i < 8; ++i) xv[i] = (float4){0.f, 0.f, 0.f, 0.f};
  }
}

__device__ __forceinline__ void proc_write(char* buf, int r, int g,
    const uint4* hv, const float4* xv, const float* scsh) {
  unsigned wv[16];
  const unsigned* hu = (const unsigned*)hv;
  const float* xf = (const float*)xv;
  #pragma unroll
  for (int j = 0; j < 16; ++j) {
    int c = g * 32 + 2 * j;
    float lo = bf2f(hu[j] & 0xffffu) * scsh[c]     + scsh[256 + c]     + xf[2 * j];
    float hi = bf2f(hu[j] >> 16)     * scsh[c + 1] + scsh[256 + c + 1] + xf[2 * j + 1];
    wv[j] = pkbf(fmaxf(lo, 0.f), fmaxf(hi, 0.f));
  }
  #pragma unroll
  for (int i = 0; i < 4; ++i) {
    int slot = ((g ^ r ^ i) & 7) | (i << 3);
    *(uint4*)(buf + r * 512 + slot * 16) = ((uint4*)wv)[i];
  }
}

// ---------------- K5: persistent pipelined BN+res+relu + MFMA fc GEMM (in-place) ----------------
__global__ __launch_bounds__(512, 4) void k_fc(
    const float* __restrict__ x, const float* __restrict__ fcb,
    float* __restrict__ ws, float* __restrict__ out, int N, int nT) {
  __shared__ __align__(16) char smem[65536];
  __shared__ float scsh[512];
  int t = threadIdx.x;
  int l = t & 63, w = t >> 6;
  int r = t >> 3, g = t & 7;
  scsh[t] = ws[SCALE_OFF + t];   // SCALE(256) then SHIFT(256) contiguous
  const unsigned short* Fpk = (const unsigned short*)(ws + FCPK_OFF);
  const unsigned* hp = (const unsigned*)out;
  int step = gridDim.x;
  int tile = blockIdx.x;
  uint4 hv[4]; float4 xv[8];
  load_fc(hp, x, tile * 64 + r, (tile * 64 + r) < N, g, hv, xv);
  float bias = fcb[(w << 4) + (l & 15)];
  __syncthreads();   // scsh ready
  proc_write(smem, r, g, hv, xv, scsh);
  __syncthreads();
  int cur = 0;
  while (true) {
    int nxt = tile + step;
    bool hasN = nxt < nT;
    if (hasN) {
      int row = nxt * 64 + r;
      load_fc(hp, x, row, row < N, g, hv, xv);   // issue early
    }
    // ---- MFMA K=256 on buf[cur] ----
    char* buf = smem + cur * 32768;
    f32x4 acc[4];
    #pragma unroll
    for (int mt = 0; mt < 4; ++mt) acc[mt] = (f32x4){0.f, 0.f, 0.f, 0.f};
    #pragma unroll
    for (int kb = 0; kb < 8; ++kb) {
      bf16x8 bfr = *(const bf16x8*)(Fpk + ((w * 8 + kb) * 64 + l) * 8);
      #pragma unroll
      for (int mt = 0; mt < 4; ++mt) {
        int rr = mt * 16 + (l & 15);
        int slot = ((kb ^ rr ^ (l >> 4)) & 7) | ((l >> 4) << 3);
        bf16x8 af = *(const bf16x8*)(buf + rr * 512 + slot * 16);
        acc[mt] = __builtin_amdgcn_mfma_f32_16x16x32_bf16(af, bfr, acc[mt], 0, 0, 0);
      }
    }
    __syncthreads();   // done reading buf[cur]
    // ---- epilogue: bias+relu, swizzled f32 transpose ----
    #pragma unroll
    for (int mt = 0; mt < 4; ++mt)
      #pragma unroll
      for (int rr = 0; rr < 4; ++rr) {
        int orow = mt * 16 + ((l >> 4) << 2) + rr;
        int col = (w << 4) + (l & 15);
        int c = col >> 2;
        int ec = ((c ^ orow) & 7) | (c & 24);
        *(float*)(buf + orow * 512 + ec * 16 + (col & 3) * 4) = fmaxf(acc[mt][rr] + bias, 0.f);
      }
    __syncthreads();
    // ---- coalesced out store + stage next ----
    int row0 = tile * 64;
    #pragma unroll
    for (int p = 0; p < 4; ++p) {
      int e = p * 512 + t; int rr = e >> 5, v4 = e & 31;
      int ec = ((v4 ^ rr) & 7) | (v4 & 24);
      float4 val = *(const float4*)(buf + rr * 512 + ec * 16);
      if (row0 + rr < N) ((float4*)out)[(size_t)(row0 + rr) * 32 + v4] = val;
    }
    if (!hasN) break;
    proc_write(smem + (cur ^ 1) * 32768, r, g, hv, xv, scsh);
    __syncthreads();
    tile = nxt; cur ^= 1;
  }
}

extern "C" void kernel_launch(void* const* d_in, const int* in_sizes, int n_in,
                              void* d_out, int out_size, void* d_ws, size_t ws_size,
                              hipStream_t stream) {
  const float* x    = (const float*)d_in[0];
  const float* rdf  = (const float*)d_in[1];
  const float* bdf  = (const float*)d_in[2];
  const int*   aidx = (const int*)d_in[3];
  const int*   eidx = (const int*)d_in[4];
  const float* rdfW = (const float*)d_in[5];
  const float* rdfG = (const float*)d_in[7];
  const float* rdfBe= (const float*)d_in[8];
  const float* bdfW = (const float*)d_in[9];
  const float* bdfG = (const float*)d_in[11];
  const float* bdfBe= (const float*)d_in[12];
  const float* fcW  = (const float*)d_in[13];
  const float* fcB  = (const float*)d_in[14];
  float* out = (float*)d_out;
  float* ws  = (float*)d_ws;
  int N = in_sizes[0] / 128;
  int nT = (N + 63) / 64;
  int grid = 512; if (grid > nT) grid = nT;

  hipMemsetAsync(d_ws, 0, (size_t)ZERO_WORDS * 4, stream);
  k_prep<<<160, 512, 0, stream>>>(rdfW, bdfW, fcW, ws);
  k_seg<<<(N + 255) / 256, 256, 0, stream>>>(x, aidx, eidx, ws, N);
  k_fin<<<2048, 256, 0, stream>>>(ws);
  k_gemm<<<grid, 512, 0, stream>>>(rdf, bdf, aidx, eidx, ws, (unsigned*)d_out, N, nT);
  k_bnfin<<<1, 256, 0, stream>>>(rdfG, rdfBe, bdfG, bdfBe, ws, N);
  k_fc<<<grid, 512, 0, stream>>>(x, fcB, ws, out, N, nT);
}

// Round 5
// 482.898 us; speedup vs baseline: 1.8406x; 1.8406x over previous
//
#include <hip/hip_runtime.h>
#include <hip/hip_bf16.h>

#define N_GRAPHS 4096
#define N_ELE 16384
#define EPS 1e-5f

// ws layout (f32 words)
#define A_TAB_OFF 0               // 4096*64 f32 atomic sums
#define A_CNT_OFF 262144          // 4096
#define E_TAB_OFF 266240          // 16384*64
#define E_CNT_OFF 1314816         // 16384
#define STAT_OFF  1331200         // 32 copies * (256 sums + 256 sqs)
#define ZPAD_OFF  1347584         // 16B guaranteed-zero pad (OOB gload_lds target)
#define ZERO_WORDS 1347588        // memset range: everything above
#define A_TABH_OFF 1347600        // 4096*64 bf16 = 131072 words
#define E_TABH_OFF 1478672        // 16384*64 bf16 = 524288 words
#define W1PK_OFF  2002960         // 2 * 128*192 bf16 = 24576 words
#define FCPK_OFF  2027536         // 128*256 bf16 = 16384 words
#define SCALE_OFF 2043920         // 256
#define SHIFT_OFF 2044176         // 256
#define WS_WORDS  2044432         // ~8.2 MB

typedef __attribute__((ext_vector_type(8))) short bf16x8;
typedef __attribute__((ext_vector_type(4))) float f32x4;

__device__ __forceinline__ float bf2f(unsigned s) { return __uint_as_float(s << 16); }
__device__ __forceinline__ unsigned f2bf(float f) {
  unsigned u = __float_as_uint(f);
  return (u + 0x7fffu + ((u >> 16) & 1u)) >> 16;  // RNE
}
__device__ __forceinline__ unsigned pkbf(float a, float b) {
  union { __hip_bfloat16 h; unsigned short u; } ca, cb;
  ca.h = __float2bfloat16(a); cb.h = __float2bfloat16(b);
  return (unsigned)ca.u | ((unsigned)cb.u << 16);
}
__device__ __forceinline__ void gload16(const void* g, void* l) {
  __builtin_amdgcn_global_load_lds(
      (const __attribute__((address_space(1))) unsigned*)g,
      (__attribute__((address_space(3))) unsigned*)l, 16, 0, 0);
}

// LDS tile geometry (k_gemm): zA = smem[0:16K]  rows[64] x 256B (rdf|bdf bf16)
//                             zB = smem[16K:32K] rows[64] x 256B (pa|pe bf16)
// 16B chunk c of row r stored at slot S = (c&8) | ((c^r)&7)  (involutive XOR swizzle).

// ---------------- K0: pack W1,W2,fcW to bf16 in MFMA B-fragment order ----------------
__global__ void k_prep(const float* __restrict__ W1, const float* __restrict__ W2,
                       const float* __restrict__ fcW, float* __restrict__ ws) {
  int tid = blockIdx.x * 512 + threadIdx.x;
  if (tid < 49152) {
    unsigned short* wpk = (unsigned short*)(ws + W1PK_OFF);
    int L = tid / 24576, rem = tid % 24576;
    int ct = rem / 3072, rem2 = rem % 3072;
    int i = rem2 >> 9, lane = (rem2 >> 3) & 63, j = rem2 & 7;
    int zkb = L ? (i + 2) : (i < 2 ? i : i + 2);
    int zk = zkb * 32 + ((lane >> 4) << 3) + j;
    int kp = L ? (zk - 64) : (zk < 64 ? zk : zk - 64);
    int col = ct * 16 + (lane & 15);
    const float* W = L ? W2 : W1;
    wpk[tid] = (unsigned short)f2bf(W[col * 192 + kp]);
  } else {  // R4 bug was here: `else if (tid < 65536)` dropped fc col-tiles 4..7
    int idx = tid - 49152;  // 0..32767, grid is exactly 81920 threads
    unsigned short* fpk = (unsigned short*)(ws + FCPK_OFF);
    int ct = idx >> 12, kb = (idx >> 9) & 7, lane = (idx >> 3) & 63, j = idx & 7;
    fpk[idx] = (unsigned short)f2bf(fcW[(ct * 16 + (lane & 15)) * 256 + kb * 32 + ((lane >> 4) << 3) + j]);
  }
}

// ---------------- K1: segment sums ----------------
__global__ void k_seg(const float* __restrict__ x, const int* __restrict__ aidx,
                      const int* __restrict__ eidx, float* __restrict__ ws, int N) {
  float* A_tab = ws + A_TAB_OFF; float* A_cnt = ws + A_CNT_OFF;
  float* E_tab = ws + E_TAB_OFF; float* E_cnt = ws + E_CNT_OFF;
  int t = threadIdx.x;
  int c = t & 63, p = (t >> 6) & 1, s = t >> 7;
  int r0 = blockIdx.x * 256;
  int rend = min(r0 + 256, N);
  if (p == 0) {
    float acc = 0.f, cnt = 0.f; int cur = -1;
    for (int r = r0 + s; r < rend; r += 2) {
      int a = aidx[r];
      float v = x[(size_t)r * 128 + c];
      if (a != cur) {
        if (cur >= 0) { atomicAdd(&A_tab[cur * 64 + c], acc); if (c == 0) atomicAdd(&A_cnt[cur], cnt); }
        cur = a; acc = v; cnt = 1.f;
      } else { acc += v; cnt += 1.f; }
    }
    if (cur >= 0) { atomicAdd(&A_tab[cur * 64 + c], acc); if (c == 0) atomicAdd(&A_cnt[cur], cnt); }
  } else {
    for (int r = r0 + s; r < rend; r += 2) {
      int e = eidx[r];
      float v = x[(size_t)r * 128 + 64 + c];
      atomicAdd(&E_tab[e * 64 + c], v);
      if (c == 0) atomicAdd(&E_cnt[e], 1.f);
    }
  }
}

// ---------------- K2: mean + relu -> bf16 tables ----------------
__global__ void k_fin(float* __restrict__ ws) {
  int i = blockIdx.x * 256 + threadIdx.x;
  unsigned* w32 = (unsigned*)ws;
  if (i < 131072) {
    int e = 2 * i;
    float cnt = fmaxf(ws[A_CNT_OFF + (e >> 6)], 1.f);
    float v0 = fmaxf(ws[A_TAB_OFF + e] / cnt, 0.f);
    float v1 = fmaxf(ws[A_TAB_OFF + e + 1] / cnt, 0.f);
    w32[A_TABH_OFF + i] = f2bf(v0) | (f2bf(v1) << 16);
  }
  if (i < 524288) {
    int e = 2 * i;
    float cnt = fmaxf(ws[E_CNT_OFF + (e >> 6)], 1.f);
    float v0 = fmaxf(ws[E_TAB_OFF + e] / cnt, 0.f);
    float v1 = fmaxf(ws[E_TAB_OFF + e + 1] / cnt, 0.f);
    w32[E_TABH_OFF + i] = f2bf(v0) | (f2bf(v1) << 16);
  }
}

// ---------------- K3: MFMA dual GEMM, async gather staging, fused BN stats ----------------
__global__ __launch_bounds__(512) void k_gemm(
    const float* __restrict__ rdf, const float* __restrict__ bdf,
    const int* __restrict__ aidx, const int* __restrict__ eidx,
    float* __restrict__ ws, unsigned* __restrict__ outp, int N) {
  __shared__ __align__(16) char smem[32768];
  const unsigned short* Atabh = (const unsigned short*)(ws + A_TABH_OFF);
  const unsigned short* Etabh = (const unsigned short*)(ws + E_TABH_OFF);
  const void* zpad = (const void*)(ws + ZPAD_OFF);
  int t = threadIdx.x;
  int l = t & 63, w = t >> 6;
  int row0 = blockIdx.x * 64;

  // ---- zB: pa/pe gathers via global_load_lds, pre-swizzled per-lane source ----
  #pragma unroll
  for (int ii = 0; ii < 2; ++ii) {
    int rb = (w * 2 + ii) * 4;            // 4 rows per wave-issue
    int r = rb + (l >> 4);
    int srow = row0 + r;
    bool ok = srow < N;
    int s = l & 15;
    int c = (s & 8) | ((s ^ r) & 7);      // logical chunk landing at slot s
    const void* src;
    if (c < 8) {
      int ia = ok ? aidx[srow] : 0;
      src = (const void*)(Atabh + ((size_t)ia * 64 + c * 8));
    } else {
      int ie = ok ? eidx[srow] : 0;
      src = (const void*)(Etabh + ((size_t)ie * 64 + (c - 8) * 8));
    }
    if (!ok) src = zpad;
    gload16(src, smem + 16384 + rb * 256);
  }

  // ---- zA: rdf/bdf f32 -> bf16, short-lived reg staging, swizzled LDS write ----
  {
    int r = t >> 3, c0 = (t & 7) * 2;
    int row = row0 + r;
    bool ok = row < N;
    #pragma unroll
    for (int cc = 0; cc < 2; ++cc) {
      int c = c0 + cc;
      uint4 wv;
      if (ok) {
        const float4* src = (const float4*)(c < 8 ? rdf + (size_t)row * 64 + c * 8
                                                  : bdf + (size_t)row * 64 + (c - 8) * 8);
        float4 f0 = src[0], f1 = src[1];
        wv.x = pkbf(f0.x, f0.y); wv.y = pkbf(f0.z, f0.w);
        wv.z = pkbf(f1.x, f1.y); wv.w = pkbf(f1.z, f1.w);
      } else wv = (uint4){0u, 0u, 0u, 0u};
      int slot = (c & 8) | ((c ^ r) & 7);
      *(uint4*)(smem + r * 256 + slot * 16) = wv;
    }
  }
  __syncthreads();   // drains vmcnt(0) incl. global_load_lds

  // ---- MFMA: wave w -> layer L = w>>2, col-pair ctp = w&3 ----
  int L = w >> 2, ctp = w & 3;
  const unsigned short* WpkL = (const unsigned short*)(ws + W1PK_OFF) + L * 24576;
  f32x4 acc[4][2];
  #pragma unroll
  for (int mt = 0; mt < 4; ++mt)
    #pragma unroll
    for (int cti = 0; cti < 2; ++cti) acc[mt][cti] = (f32x4){0.f, 0.f, 0.f, 0.f};
  int half = l >> 4;
  #pragma unroll
  for (int i = 0; i < 6; ++i) {
    int zkb = L ? (i + 2) : (i < 2 ? i : i + 2);
    int cg = zkb * 4 + half;
    const char* base = smem + (zkb < 4 ? 0 : 16384);
    int cl = cg & 15;
    bf16x8 af[4];
    #pragma unroll
    for (int mt = 0; mt < 4; ++mt) {
      int rr = mt * 16 + (l & 15);
      int slot = (cl & 8) | ((cl ^ rr) & 7);
      af[mt] = *(const bf16x8*)(base + rr * 256 + slot * 16);
    }
    #pragma unroll
    for (int cti = 0; cti < 2; ++cti) {
      bf16x8 bfr = *(const bf16x8*)(WpkL + (((ctp * 2 + cti) * 6 + i) * 64 + l) * 8);
      #pragma unroll
      for (int mt = 0; mt < 4; ++mt)
        acc[mt][cti] = __builtin_amdgcn_mfma_f32_16x16x32_bf16(af[mt], bfr, acc[mt][cti], 0, 0, 0);
    }
  }

  // ---- fused BN stats: reduce -> 32-copy atomics ----
  float* stat = ws + STAT_OFF + (blockIdx.x & 31) * 512;
  #pragma unroll
  for (int cti = 0; cti < 2; ++cti) {
    float s = 0.f, q = 0.f;
    #pragma unroll
    for (int mt = 0; mt < 4; ++mt)
      #pragma unroll
      for (int rr = 0; rr < 4; ++rr) { float v = acc[mt][cti][rr]; s += v; q += v * v; }
    s += __shfl_xor(s, 16); s += __shfl_xor(s, 32);
    q += __shfl_xor(q, 16); q += __shfl_xor(q, 32);
    if (l < 16) {
      int gc = L * 128 + ctp * 32 + cti * 16 + l;
      atomicAdd(&stat[gc], s);
      atomicAdd(&stat[256 + gc], q);
    }
  }
  __syncthreads();   // all waves done reading z

  // ---- epilogue: pack bf16 pairs, swizzled LDS transpose ----
  #pragma unroll
  for (int mt = 0; mt < 4; ++mt)
    #pragma unroll
    for (int cti = 0; cti < 2; ++cti)
      #pragma unroll
      for (int rr = 0; rr < 4; ++rr) {
        unsigned ub = pkbf(acc[mt][cti][rr], 0.f) & 0xffffu;
        unsigned pb = (unsigned)__shfl_xor((int)ub, 1);
        if (!(l & 1)) {
          int orow = mt * 16 + ((l >> 4) << 2) + rr;
          int colp = (L * 128 + ctp * 32 + cti * 16 + (l & 15)) >> 1;
          int c = colp >> 2;
          int ec = ((c ^ orow) & 7) | (c & 24);
          *(unsigned*)(smem + orow * 512 + ec * 16 + (colp & 3) * 4) = ub | (pb << 16);
        }
      }
  __syncthreads();
  #pragma unroll
  for (int p = 0; p < 4; ++p) {
    int e = p * 512 + t; int rr = e >> 5, v4 = e & 31;
    int ec = ((v4 ^ rr) & 7) | (v4 & 24);
    uint4 val = *(const uint4*)(smem + rr * 512 + ec * 16);
    if (row0 + rr < N) ((uint4*)outp)[(size_t)(row0 + rr) * 32 + v4] = val;
  }
}

// ---------------- K4: BN finalize -> scale/shift ----------------
__global__ void k_bnfin(const float* __restrict__ g1, const float* __restrict__ b1,
                        const float* __restrict__ g2, const float* __restrict__ b2,
                        float* __restrict__ ws, int N) {
  int c = threadIdx.x;  // 256
  float s = 0.f, q = 0.f;
  for (int m = 0; m < 32; ++m) { s += ws[STAT_OFF + m * 512 + c]; q += ws[STAT_OFF + m * 512 + 256 + c]; }
  float inv = 1.f / (float)N;
  float mu = s * inv;
  float var = fmaxf(q * inv - mu * mu, 0.f);
  int lyr = c >> 7, cc = c & 127;
  float ga = lyr ? g2[cc] : g1[cc];
  float be = lyr ? b2[cc] : b1[cc];
  float sc = ga * rsqrtf(var + EPS);
  ws[SCALE_OFF + c] = sc;
  ws[SHIFT_OFF + c] = be - mu * sc;
}

// ---------------- K5: BN apply + residual + relu + MFMA fc GEMM (in-place on d_out) ----------------
__global__ __launch_bounds__(512) void k_fc(
    const float* __restrict__ x, const float* __restrict__ fcb,
    float* __restrict__ ws, float* __restrict__ out, int N) {
  __shared__ __align__(16) char smem[32768];
  __shared__ float scsh[512];
  int t = threadIdx.x;
  int l = t & 63, w = t >> 6;
  int r = t >> 3, g = t & 7;
  const unsigned* hp = (const unsigned*)out;
  int row0 = blockIdx.x * 64;
  int row = row0 + r;
  bool ok = row < N;
  // ---- load h + x (short residency) ----
  uint4 hv[4]; float4 xv[8];
  if (ok) {
    const uint4* hs = (const uint4*)(hp + (size_t)row * 128 + g * 16);
    #pragma unroll
    for (int i = 0; i < 4; ++i) hv[i] = hs[i];
    const float4* xs = (const float4*)(x + (size_t)row * 128 + (g & 3) * 32);
    #pragma unroll
    for (int i = 0; i < 8; ++i) xv[i] = xs[i];
  } else {
    #pragma unroll
    for (int i = 0; i < 4; ++i) hv[i] = (uint4){0u, 0u, 0u, 0u};
    #pragma unroll
    for (int i = 0; i < 8; ++i) xv[i] = (float4){0.f, 0.f, 0.f, 0.f};
  }
  scsh[t] = ws[SCALE_OFF + t];
  __syncthreads();
  // ---- BN + residual + relu -> bf16, swizzled LDS write ----
  {
    unsigned wv[16];
    const unsigned* hu = (const unsigned*)hv;
    const float* xf = (const float*)xv;
    #pragma unroll
    for (int j = 0; j < 16; ++j) {
      int c = g * 32 + 2 * j;
      float lo = bf2f(hu[j] & 0xffffu) * scsh[c]     + scsh[256 + c]     + xf[2 * j];
      float hi = bf2f(hu[j] >> 16)     * scsh[c + 1] + scsh[256 + c + 1] + xf[2 * j + 1];
      wv[j] = pkbf(fmaxf(lo, 0.f), fmaxf(hi, 0.f));
    }
    #pragma unroll
    for (int i = 0; i < 4; ++i) {
      int slot = ((g ^ r ^ i) & 7) | (i << 3);
      *(uint4*)(smem + r * 512 + slot * 16) = ((uint4*)wv)[i];
    }
  }
  __syncthreads();
  // ---- MFMA K=256: wave w -> col-tile w ----
  f32x4 acc[4];
  #pragma unroll
  for (int mt = 0; mt < 4; ++mt) acc[mt] = (f32x4){0.f, 0.f, 0.f, 0.f};
  const unsigned short* Fpk = (const unsigned short*)(ws + FCPK_OFF);
  int half = l >> 4;
  #pragma unroll
  for (int kb = 0; kb < 8; ++kb) {
    bf16x8 bfr = *(const bf16x8*)(Fpk + ((w * 8 + kb) * 64 + l) * 8);
    #pragma unroll
    for (int mt = 0; mt < 4; ++mt) {
      int rr = mt * 16 + (l & 15);
      int slot = ((kb ^ rr ^ half) & 7) | (half << 3);
      bf16x8 af = *(const bf16x8*)(smem + rr * 512 + slot * 16);
      acc[mt] = __builtin_amdgcn_mfma_f32_16x16x32_bf16(af, bfr, acc[mt], 0, 0, 0);
    }
  }
  float bias = fcb[(w << 4) + (l & 15)];
  __syncthreads();
  // ---- epilogue: bias + relu, swizzled f32 transpose ----
  #pragma unroll
  for (int mt = 0; mt < 4; ++mt)
    #pragma unroll
    for (int rr = 0; rr < 4; ++rr) {
      int orow = mt * 16 + ((l >> 4) << 2) + rr;
      int col = (w << 4) + (l & 15);
      int c = col >> 2;
      int ec = ((c ^ orow) & 7) | (c & 24);
      *(float*)(smem + orow * 512 + ec * 16 + (col & 3) * 4) = fmaxf(acc[mt][rr] + bias, 0.f);
    }
  __syncthreads();
  #pragma unroll
  for (int p = 0; p < 4; ++p) {
    int e = p * 512 + t; int rr = e >> 5, v4 = e & 31;
    int ec = ((v4 ^ rr) & 7) | (v4 & 24);
    float4 val = *(const float4*)(smem + rr * 512 + ec * 16);
    if (row0 + rr < N) ((float4*)out)[(size_t)(row0 + rr) * 32 + v4] = val;
  }
}

extern "C" void kernel_launch(void* const* d_in, const int* in_sizes, int n_in,
                              void* d_out, int out_size, void* d_ws, size_t ws_size,
                              hipStream_t stream) {
  const float* x    = (const float*)d_in[0];
  const float* rdf  = (const float*)d_in[1];
  const float* bdf  = (const float*)d_in[2];
  const int*   aidx = (const int*)d_in[3];
  const int*   eidx = (const int*)d_in[4];
  const float* rdfW = (const float*)d_in[5];
  const float* rdfG = (const float*)d_in[7];
  const float* rdfBe= (const float*)d_in[8];
  const float* bdfW = (const float*)d_in[9];
  const float* bdfG = (const float*)d_in[11];
  const float* bdfBe= (const float*)d_in[12];
  const float* fcW  = (const float*)d_in[13];
  const float* fcB  = (const float*)d_in[14];
  float* out = (float*)d_out;
  float* ws  = (float*)d_ws;
  int N = in_sizes[0] / 128;
  int nT = (N + 63) / 64;

  hipMemsetAsync(d_ws, 0, (size_t)ZERO_WORDS * 4, stream);
  k_prep<<<160, 512, 0, stream>>>(rdfW, bdfW, fcW, ws);
  k_seg<<<(N + 255) / 256, 256, 0, stream>>>(x, aidx, eidx, ws, N);
  k_fin<<<2048, 256, 0, stream>>>(ws);
  k_gemm<<<nT, 512, 0, stream>>>(rdf, bdf, aidx, eidx, ws, (unsigned*)d_out, N);
  k_bnfin<<<1, 256, 0, stream>>>(rdfG, rdfBe, bdfG, bdfBe, ws, N);
  k_fc<<<nT, 512, 0, stream>>>(x, fcB, ws, out, N);
}